// Round 5
// baseline (314.408 us; speedup 1.0000x reference)
//
#include <hip/hip_runtime.h>
#include <hip/hip_bf16.h>
#include <math.h>

// ---------------- workspace layout (floats) ----------------
#define WS_YSUM  20480        // 40
#define WS_XMAX  20520        // 8
#define WS_HIST  20528        // 816 (int)
#define WS_THR   21344        // 32
#define WS_MN    21376        // 40 (uint)
#define WS_MX    21440        // 40 (uint)
#define WS_XP    21504        // 8*3*256*256 = 1572864 ; reused for At (fp32) after conv7
#define WS_IA    1594368      // 8*256*256   = 524288
#define WS_XGL   2118656      // 8*256*256   = 524288

#define GDM_OUT  655360       // 8*5*128*128

static __device__ __forceinline__ float xv_val(int i) {
    double t = (double)i / 100.0;
    return (float)(10.0 * t * t * t);
}

// ---- G1: avgpool 3x3 s2 p1 on x[8,3,512,512] -> xp[8,3,256,256], ia = channel mean ----
__global__ __launch_bounds__(256) void k_pool3_mean(const float* __restrict__ x,
                                                    float* __restrict__ xp,
                                                    float* __restrict__ ia) {
    int idx = blockIdx.x * 256 + threadIdx.x;
    if (idx >= 8 * 256 * 256) return;
    int b = idx >> 16; int p = idx & 65535; int oy = p >> 8; int ox = p & 255;
    float cs[3];
#pragma unroll
    for (int c = 0; c < 3; ++c) {
        const float* src = x + (((size_t)(b * 3 + c)) << 18);
        float s = 0.f;
#pragma unroll
        for (int dy = -1; dy <= 1; ++dy) {
            int iy = 2 * oy + dy; if ((unsigned)iy >= 512u) continue;
#pragma unroll
            for (int dx = -1; dx <= 1; ++dx) {
                int ix = 2 * ox + dx; if ((unsigned)ix >= 512u) continue;
                s += src[iy * 512 + ix];
            }
        }
        cs[c] = s * (1.f / 9.f);
        xp[(((size_t)(b * 3 + c)) << 16) + p] = cs[c];
    }
    ia[(((size_t)b) << 16) + p] = (cs[0] + cs[1] + cs[2]) * (1.f / 3.f);
}

// ---- G2: conv7x7 s2 p3 on xp -> spatial sums per (b,co) ----
__global__ __launch_bounds__(256) void k_conv7_reduce(const float* __restrict__ xp,
                                                      const float* __restrict__ w,
                                                      float* __restrict__ ysum) {
    int co = blockIdx.y, b = blockIdx.z;
    int p = blockIdx.x * 256 + threadIdx.x;
    int oy = p >> 7, ox = p & 127;
    __shared__ float wsm[147];
    if (threadIdx.x < 147) wsm[threadIdx.x] = w[co * 147 + threadIdx.x];
    __syncthreads();
    float s = 0.f;
    for (int ic = 0; ic < 3; ++ic) {
        const float* src = xp + (((size_t)(b * 3 + ic)) << 16);
#pragma unroll
        for (int r = 0; r < 7; ++r) {
            int iy = 2 * oy - 3 + r; if ((unsigned)iy >= 256u) continue;
#pragma unroll
            for (int ss = 0; ss < 7; ++ss) {
                int ix = 2 * ox - 3 + ss; if ((unsigned)ix >= 256u) continue;
                s += wsm[(ic * 7 + r) * 7 + ss] * src[iy * 256 + ix];
            }
        }
    }
    __shared__ float red[256];
    red[threadIdx.x] = s; __syncthreads();
    for (int off = 128; off > 0; off >>= 1) {
        if (threadIdx.x < off) red[threadIdx.x] += red[threadIdx.x + off];
        __syncthreads();
    }
    if (threadIdx.x == 0) atomicAdd(&ysum[b * 5 + co], red[0]);
}

// ---- G4: x_GL = |conv5x5(ia, a1*GL)| threshold, histogram + per-b max ----
__global__ __launch_bounds__(256) void k_gl_hist(const float* __restrict__ ia,
                                                 const float* __restrict__ gdmw,
                                                 float* __restrict__ xgl,
                                                 int* __restrict__ hist,
                                                 unsigned* __restrict__ xmax) {
    int b = blockIdx.y;
    int p = blockIdx.x * 256 + threadIdx.x;
    int y = p >> 8, x = p & 255;
    __shared__ float xv[101];
    __shared__ int sh[102];
    __shared__ float redm[256];
    if (threadIdx.x < 101) xv[threadIdx.x] = xv_val(threadIdx.x);
    if (threadIdx.x < 102) sh[threadIdx.x] = 0;
    __syncthreads();
    const float* src = ia + (((size_t)b) << 16);
    float a1 = gdmw[0] * 4.f;
    auto rd = [&](int dy, int dx) -> float {
        int iy = y + dy, ix = x + dx;
        if ((unsigned)iy >= 256u || (unsigned)ix >= 256u) return 0.f;
        return src[iy * 256 + ix];
    };
    float acc = rd(0, 0)
        - 0.125f  * (rd(-1, 0) + rd(0, -1) + rd(0, 1) + rd(1, 0))
        - 0.0625f * (rd(-2, 0) + rd(-1, -1) + rd(-1, 1) + rd(0, -2) +
                     rd(0, 2) + rd(1, -1) + rd(1, 1) + rd(2, 0));
    float raw = fabsf(a1 * acc);
    float val = (raw < 1e-6f) ? 0.f : raw;
    xgl[(((size_t)b) << 16) + p] = val;
    if (val > 0.f) {
        int lo = 0, hi = 101;
        while (lo < hi) { int mid = (lo + hi) >> 1; if (val <= xv[mid]) hi = mid; else lo = mid + 1; }
        atomicAdd(&sh[lo], 1);
    }
    redm[threadIdx.x] = val; __syncthreads();
    for (int off = 128; off > 0; off >>= 1) {
        if (threadIdx.x < off) redm[threadIdx.x] = fmaxf(redm[threadIdx.x], redm[threadIdx.x + off]);
        __syncthreads();
    }
    if (threadIdx.x == 0) atomicMax(&xmax[b], __float_as_uint(redm[0]));
    if (threadIdx.x < 102 && sh[threadIdx.x]) atomicAdd(&hist[b * 102 + threadIdx.x], sh[threadIdx.x]);
}

// ---- G5: thresholds + init of pool min/max accumulators ----
__global__ void k_thresholds(const float* __restrict__ ysum, const float* __restrict__ gamma,
                             const float* __restrict__ beta, const float* __restrict__ mean,
                             const float* __restrict__ var, const int* __restrict__ hist,
                             float* __restrict__ thr, unsigned* __restrict__ mnb,
                             unsigned* __restrict__ mxb) {
    int b = threadIdx.x;
    if (b >= 8) {
        if (b < 48) { mnb[b - 8] = 0x7f7fffffu; mxb[b - 8] = 0u; }
        return;
    }
    float wa[5];
    for (int c = 1; c < 5; ++c) {
        float m = ysum[b * 5 + c] * (1.f / 16384.f);
        wa[c] = tanhf((m - mean[c]) * rsqrtf(var[c] + 1e-5f) * gamma[c] + beta[c]);
    }
    float pr[4] = {0.2f + 0.05f * wa[1], 0.4f + 0.05f * wa[2],
                   0.6f + 0.05f * wa[3], 0.8f + 0.05f * wa[4]};
    auto sw = [&](int i, int j) { if (pr[i] > pr[j]) { float t = pr[i]; pr[i] = pr[j]; pr[j] = t; } };
    sw(0, 1); sw(2, 3); sw(0, 2); sw(1, 3); sw(1, 2);
    int all = 0;
    for (int i = 0; i <= 101; ++i) all += hist[b * 102 + i];
    float bestz[4] = {1e30f, 1e30f, 1e30f, 1e30f};
    int besti[4] = {0, 0, 0, 0};
    int cum = 0;
    for (int i = 0; i <= 100; ++i) {
        cum += hist[b * 102 + i];
        float pct = (float)cum / (float)all;
        for (int t = 0; t < 4; ++t) {
            float z = fabsf(pct - pr[t]);
            if (z < bestz[t]) { bestz[t] = z; besti[t] = i; }
        }
    }
    for (int t = 0; t < 4; ++t) thr[b * 4 + t] = xv_val(besti[t]);
}

// ---- fused (optional mask) + h-box9 + v-box9, stride-1, 8 output rows / block ----
#define F1_STR 268
template<bool MASK>
__global__ __launch_bounds__(256) void k_hv(const float* __restrict__ in,
                                            const float* __restrict__ thr,
                                            const unsigned* __restrict__ xmax,
                                            float* __restrict__ outp) {
    int plane = blockIdx.y;          // 0..39
    int r0 = blockIdx.x * 8;         // output rows r0..r0+7
    float tmin = 0.f, tmax = 0.f;
    const float* src;
    if (MASK) {
        int b = plane / 5, band = plane - 5 * b;
        tmin = (band == 0) ? 0.f : thr[b * 4 + band - 1];
        tmax = (band == 4) ? __uint_as_float(xmax[b]) : thr[b * 4 + band];
        src = in + (((size_t)b) << 16);
    } else {
        src = in + (((size_t)plane) << 16);
    }
    __shared__ float mr[16][F1_STR];
    __shared__ float hh[16][256];
    int tid = threadIdx.x;
    for (int l = tid; l < 16 * 256; l += 256) {
        int i = l >> 8, c = l & 255;
        int rr = r0 - 4 + i;
        float v = ((unsigned)rr < 256u) ? src[rr * 256 + c] : 0.f;
        if (MASK) v = (v > tmin && v <= tmax) ? 1.f : 0.f;
        mr[i][c + 4] = v;
    }
    if (tid < 128) { int i = tid >> 3, p = tid & 7; mr[i][p < 4 ? p : 256 + p] = 0.f; }
    __syncthreads();
    {
        int r = tid >> 4, x0 = (tid & 15) * 16;
        float w[24];
#pragma unroll
        for (int k = 0; k < 6; ++k) {
            float4 q = *(const float4*)&mr[r][x0 + 4 * k];
            w[4 * k] = q.x; w[4 * k + 1] = q.y; w[4 * k + 2] = q.z; w[4 * k + 3] = q.w;
        }
        float o[16];
        float s = 0.f;
#pragma unroll
        for (int k = 0; k < 9; ++k) s += w[k];
#pragma unroll
        for (int j = 0; j < 16; ++j) {
            o[j] = s * (1.f / 9.f);
            if (j < 15) s += w[j + 9] - w[j];
        }
#pragma unroll
        for (int k = 0; k < 4; ++k) {
            float4 q = {o[4 * k], o[4 * k + 1], o[4 * k + 2], o[4 * k + 3]};
            *(float4*)&hh[r][x0 + 4 * k] = q;
        }
    }
    __syncthreads();
    {
        int c = tid;
        float ld[16];
#pragma unroll
        for (int i = 0; i < 16; ++i) ld[i] = hh[i][c];
        float s = 0.f;
#pragma unroll
        for (int k = 0; k < 9; ++k) s += ld[k];
        float* dst = outp + (((size_t)plane) << 16);
#pragma unroll
        for (int j = 0; j < 8; ++j) {
            dst[(r0 + j) * 256 + c] = s * (1.f / 9.f);
            if (j < 7) s += ld[j + 9] - ld[j];
        }
    }
}

// ---- fused h-box9(s2) + v-box9(s2) + per-plane min/max atomics ----
#define F3_STR 264
__global__ __launch_bounds__(256) void k_hv_s2(const float* __restrict__ in,
                                               float* __restrict__ outp,
                                               unsigned* __restrict__ mnb,
                                               unsigned* __restrict__ mxb) {
    int plane = blockIdx.y;
    int r0 = blockIdx.x * 8;
    __shared__ float mr[24][F3_STR];
    __shared__ float hh[24][128];
    int tid = threadIdx.x;
    const float* src = in + (((size_t)plane) << 16);
    for (int l = tid; l < 24 * 256; l += 256) {
        int i = l >> 8, c = l & 255;
        int rr = 2 * r0 - 4 + i;
        mr[i][c + 4] = ((unsigned)rr < 256u) ? src[rr * 256 + c] : 0.f;
    }
    if (tid < 192) { int i = tid >> 3, p = tid & 7; mr[i][p < 4 ? p : 256 + p] = 0.f; }
    __syncthreads();
    for (int l = tid; l < 24 * 128; l += 256) {
        int i = l >> 7, ox = l & 127;
        float s = 0.f;
#pragma unroll
        for (int k = 0; k < 9; ++k) s += mr[i][2 * ox + k];
        hh[i][ox] = s * (1.f / 9.f);
    }
    __syncthreads();
    float vmn = 1e30f, vmx = -1e30f;
    {
        int c = tid & 127, jh = tid >> 7;
        float* dst = outp + (size_t)plane * 16384;
#pragma unroll
        for (int q = 0; q < 4; ++q) {
            int j = jh * 4 + q;
            float s = 0.f;
#pragma unroll
            for (int k = 0; k < 9; ++k) s += hh[2 * j + k][c];
            s *= (1.f / 9.f);
            dst[(r0 + j) * 128 + c] = s;
            vmn = fminf(vmn, s); vmx = fmaxf(vmx, s);
        }
    }
    __shared__ float smn[256], smx[256];
    smn[tid] = vmn; smx[tid] = vmx; __syncthreads();
    for (int off = 128; off > 0; off >>= 1) {
        if (tid < off) {
            smn[tid] = fminf(smn[tid], smn[tid + off]);
            smx[tid] = fmaxf(smx[tid], smx[tid + off]);
        }
        __syncthreads();
    }
    if (tid == 0) {
        atomicMin(&mnb[plane], __float_as_uint(smn[0]));
        atomicMax(&mxb[plane], __float_as_uint(smx[0]));
    }
}

// ---- normalize ----
__global__ __launch_bounds__(256) void k_norm(const float* __restrict__ in,
                                              const unsigned* __restrict__ mnb,
                                              const unsigned* __restrict__ mxb,
                                              float* __restrict__ outp) {
    int i4 = blockIdx.x * 256 + threadIdx.x;
    int idx = i4 * 4;
    int plane = idx >> 14;
    float mn = __uint_as_float(mnb[plane]), mx = __uint_as_float(mxb[plane]);
    float inv = 1.f / (mx - mn);
    float4 v = *(const float4*)&in[idx];
    float4 o = {(v.x - mn) * inv, (v.y - mn) * inv, (v.z - mn) * inv, (v.w - mn) * inv};
    *(float4*)&outp[idx] = o;
}

// ---- H1: A[(d*64+c)*64+o] = scale_d * sum_m fc_w[o][d*64+m]*hw[m][c][goff_d] (fp32) ----
__global__ __launch_bounds__(256) void k_mixA(const float* __restrict__ hw,
                                              const float* __restrict__ fcw,
                                              float* __restrict__ At) {
    int idx = blockIdx.x * 256 + threadIdx.x;  // 320*64 = 20480
    if (idx >= 20480) return;
    int o = idx & 63; int k = idx >> 6;        // k = d*64+c
    int d = k >> 6; int c = k & 63;
    const int goff[5] = {0, 1, 2, 3, 8};
    float s = 0.f;
    for (int m = 0; m < 64; ++m)
        s += fcw[o * 320 + d * 64 + m] * hw[(m * 64 + c) * 9 + goff[d]];
    At[k * 64 + o] = s * ((d == 4) ? 4.f : 1.f);
}

// ---- H2: fused stencils + channel-mix (VALU, r2-verified math), 8x16 px tile, grid 1024 ----
__global__ __launch_bounds__(256) void k_hge(const float* __restrict__ feat,
                                             const float* __restrict__ At,
                                             const float* __restrict__ fcb,
                                             float* __restrict__ out) {
    int tile = blockIdx.x, b = blockIdx.y;     // 128 tiles (16 rows x 8 cols of 8x16 px)
    int ty = (tile >> 3) * 8, tx = (tile & 7) * 16;
    __shared__ float ft[504];                  // [2][12][21]
    __shared__ float tl[2][2][5][128];         // [buf][ch][dir][px]
    __shared__ float al[2][640];               // [buf][ch*320 + d*64 + o]
    int tid = threadIdx.x;
    int og = tid >> 5, pg = tid & 31;

    float acc[4][8];                           // [px j][out oi]
#pragma unroll
    for (int i = 0; i < 4; ++i)
#pragma unroll
        for (int j = 0; j < 8; ++j) acc[i][j] = 0.f;

    // staging descriptors: 480 ft (2ch x 12x20) + 640 al (2ch x 5 x 64), 5 slots/thread
    const float* gp[5]; int lofs[5]; int typ[5]; int strd[5];
#pragma unroll
    for (int j = 0; j < 5; ++j) {
        int l = tid + 256 * j;
        typ[j] = 2; gp[j] = nullptr; lofs[j] = 0; strd[j] = 0;
        if (l < 480) {
            int ch = l / 240, rem = l - ch * 240;
            int r = rem / 20, cx = rem - r * 20;
            lofs[j] = ch * 252 + r * 21 + cx;
            typ[j] = 0;
            int gy = ty - 2 + r, gx = tx - 2 + cx;
            if ((unsigned)gy < 128u && (unsigned)gx < 128u) {
                gp[j] = feat + (((size_t)(b * 64 + ch)) << 14) + gy * 128 + gx;
                strd[j] = 2 << 14;             // advance 2 channels
            }
        } else if (l < 1120) {
            int q = l - 480;
            int ch = q / 320, k = q - ch * 320; // k = d*64+o
            gp[j] = At + (k >> 6) * 4096 + ch * 64 + (k & 63);  // At[(d*64+c)*64+o], c starts at ch
            strd[j] = 128;                     // c += 2 per group
            lofs[j] = ch * 320 + k;
            typ[j] = 1;
        }
    }
    float pf[5];
#pragma unroll
    for (int j = 0; j < 5; ++j) pf[j] = gp[j] ? *gp[j] : 0.f;

    for (int g = 0; g < 32; ++g) {
        int buf = g & 1;
#pragma unroll
        for (int j = 0; j < 5; ++j) {
            if (typ[j] == 0) ft[lofs[j]] = pf[j];
            else if (typ[j] == 1) al[buf][lofs[j]] = pf[j];
        }
        __syncthreads();
        if (g < 31) {
#pragma unroll
            for (int j = 0; j < 5; ++j) if (gp[j]) { gp[j] += strd[j]; pf[j] = *gp[j]; }
        }
        // stencil: thread = (px = tid&127, ch = tid>>7)
        {
            int px = tid & 127, chs = tid >> 7;
            int cy = (px >> 4) + 2, cx = (px & 15) + 2;
            const float* F = &ft[chs * 252];
#define FF(r, c) F[(r) * 21 + (c)]
            float a  = FF(cy - 1, cx - 1), bq = FF(cy - 1, cx), cc = FF(cy - 1, cx + 1);
            float dd = FF(cy, cx - 1),     ee = FF(cy, cx),     fv = FF(cy, cx + 1);
            float g_ = FF(cy + 1, cx - 1), h  = FF(cy + 1, cx), i2 = FF(cy + 1, cx + 1);
            float u2 = FF(cy - 2, cx), d2 = FF(cy + 2, cx);
            float l2 = FF(cy, cx - 2), r2 = FF(cy, cx + 2);
#undef FF
            tl[buf][chs][0][px] = (a + 2.f * bq + cc) - (g_ + 2.f * h + i2);
            tl[buf][chs][1][px] = 2.f * a + bq + dd - fv - h - 2.f * i2;
            tl[buf][chs][2][px] = (a - cc) + 2.f * (dd - fv) + (g_ - i2);
            tl[buf][chs][3][px] = -bq - 2.f * cc + dd - fv + 2.f * g_ + h;
            tl[buf][chs][4][px] = ee - 0.125f * (bq + dd + fv + h)
                                - 0.0625f * (u2 + a + cc + l2 + r2 + g_ + i2 + d2);
        }
        __syncthreads();
        // FMA: 4 px (pg + 32*pj) x 8 outs (og*8..+7)
#pragma unroll
        for (int ch2 = 0; ch2 < 2; ++ch2) {
#pragma unroll
            for (int d = 0; d < 5; ++d) {
                float4 a0 = *(const float4*)&al[buf][ch2 * 320 + d * 64 + og * 8];
                float4 a1 = *(const float4*)&al[buf][ch2 * 320 + d * 64 + og * 8 + 4];
                float av[8] = {a0.x, a0.y, a0.z, a0.w, a1.x, a1.y, a1.z, a1.w};
                float tv[4];
#pragma unroll
                for (int pj = 0; pj < 4; ++pj) tv[pj] = tl[buf][ch2][d][pg + 32 * pj];
#pragma unroll
                for (int pj = 0; pj < 4; ++pj)
#pragma unroll
                    for (int oi = 0; oi < 8; ++oi)
                        acc[pj][oi] = fmaf(av[oi], tv[pj], acc[pj][oi]);
            }
        }
    }
    // epilogue
#pragma unroll
    for (int oi = 0; oi < 8; ++oi) {
        int o = og * 8 + oi;
        float bias = fcb[o];
        float* dsto = out + (((size_t)(b * 64 + o)) << 14);
#pragma unroll
        for (int pj = 0; pj < 4; ++pj) {
            int px = pg + 32 * pj;
            dsto[(ty + (px >> 4)) * 128 + tx + (px & 15)] = acc[pj][oi] + bias;
        }
    }
}

extern "C" void kernel_launch(void* const* d_in, const int* in_sizes, int n_in,
                              void* d_out, int out_size, void* d_ws, size_t ws_size,
                              hipStream_t stream) {
    const float* x    = (const float*)d_in[0];
    const float* gdmw = (const float*)d_in[1];
    const float* convw= (const float*)d_in[2];
    const float* bng  = (const float*)d_in[3];
    const float* bnb  = (const float*)d_in[4];
    const float* bnm  = (const float*)d_in[5];
    const float* bnv  = (const float*)d_in[6];
    const float* feat = (const float*)d_in[7];
    const float* hw   = (const float*)d_in[8];
    const float* fcw  = (const float*)d_in[9];
    const float* fcb  = (const float*)d_in[10];
    float* out = (float*)d_out;
    float* ws  = (float*)d_ws;

    float* ysum = ws + WS_YSUM;
    unsigned* xmax = (unsigned*)(ws + WS_XMAX);
    int* hist   = (int*)(ws + WS_HIST);
    float* thr  = ws + WS_THR;
    unsigned* mnb = (unsigned*)(ws + WS_MN);
    unsigned* mxb = (unsigned*)(ws + WS_MX);
    float* xp   = ws + WS_XP;
    float* ia   = ws + WS_IA;
    float* xgl  = ws + WS_XGL;
    float* At   = ws + WS_XP;          // reuses xp region (dead after conv7), 20480 floats

    // pool ping-pong buffers live in the hge half of d_out (hge written last)
    float* hge = out + GDM_OUT;
    float* p0  = hge;                  // [40][256][256]
    float* p1  = hge + 2621440;        // [40][256][256]
    float* p2  = hge + 5242880;        // [40][128][128]

    hipMemsetAsync(ws + WS_YSUM, 0, (WS_THR - WS_YSUM) * sizeof(float), stream);

    k_pool3_mean  <<<2048, 256, 0, stream>>>(x, xp, ia);
    k_conv7_reduce<<<dim3(64, 5, 8), 256, 0, stream>>>(xp, convw, ysum);
    k_mixA        <<<80, 256, 0, stream>>>(hw, fcw, At);        // xp dead from here
    k_gl_hist     <<<dim3(256, 8), 256, 0, stream>>>(ia, gdmw, xgl, hist, xmax);
    k_thresholds  <<<1, 64, 0, stream>>>(ysum, bng, bnb, bnm, bnv, hist, thr, mnb, mxb);
    k_hv<true>    <<<dim3(32, 40), 256, 0, stream>>>(xgl, thr, xmax, p0);
    k_hv<false>   <<<dim3(32, 40), 256, 0, stream>>>(p0, nullptr, nullptr, p1);
    k_hv_s2       <<<dim3(16, 40), 256, 0, stream>>>(p1, p2, mnb, mxb);
    k_norm        <<<640, 256, 0, stream>>>(p2, mnb, mxb, out);

    k_hge         <<<dim3(128, 8), 256, 0, stream>>>(feat, At, fcb, out + GDM_OUT);
}